// Round 7
// baseline (112.999 us; speedup 1.0000x reference)
//
#include <hip/hip_runtime.h>
#include <cmath>

#define S_   128
#define W_   64
#define D_   200
#define H_   50
#define OUT_ 5

// ---------------------------------------------------------------------------
// Kernel 1: one block per sentence.
//  A) sum the 64 embedding rows (per-dim threads, coalesced), grab 4 edge rows
//  B) project {full,E0,E1,E62,E63} through w_word (5*H dot-200s)
//  C) reconstruct the 6 conv-window means, apply conv weights + tanh -> reps[s]
//  D) fold in the GRNN input projections: X[g][s][o] = reps[s]@Wg.T + bg
// ---------------------------------------------------------------------------
__global__ __launch_bounds__(256) void k_sent(
    const int* __restrict__ doc, const float* __restrict__ emb,
    const float* __restrict__ w_word, const float* __restrict__ b_word,
    const float* __restrict__ cw1, const float* __restrict__ cb1,
    const float* __restrict__ cw2, const float* __restrict__ cb2,
    const float* __restrict__ cw3, const float* __restrict__ cb3,
    const float* __restrict__ Wi, const float* __restrict__ bi,
    const float* __restrict__ Wf, const float* __restrict__ bf,
    const float* __restrict__ Wr, const float* __restrict__ br,
    float* __restrict__ Xout)   // [3][S_][H_]
{
    const int s   = blockIdx.x;
    const int tid = threadIdx.x;

    __shared__ int   drow[W_];
    __shared__ float vec[5][D_];     // full sum, E0, E1, E62, E63
    __shared__ float q[5][H_];       // w_word @ each of the above
    __shared__ float m[6][H_ + 2];   // the 6 window means (k=1:1, k=2:2, k=3:3)
    __shared__ float reps_sh[H_];

    if (tid < W_) drow[tid] = doc[s * W_ + tid];
    __syncthreads();

    if (tid < D_) {
        const int d = tid;
        float acc = 0.f;
        for (int u = 0; u < W_; ++u)
            acc += emb[(size_t)drow[u] * D_ + d];
        vec[0][d] = acc;
        vec[1][d] = emb[(size_t)drow[0]      * D_ + d];
        vec[2][d] = emb[(size_t)drow[1]      * D_ + d];
        vec[3][d] = emb[(size_t)drow[W_ - 2] * D_ + d];
        vec[4][d] = emb[(size_t)drow[W_ - 1] * D_ + d];
    }
    __syncthreads();

    if (tid < 5 * H_) {
        const int v = tid / H_, h = tid % H_;
        const float* wr = w_word + h * D_;
        float acc = 0.f;
        for (int d = 0; d < D_; ++d) acc += wr[d] * vec[v][d];
        q[v][h] = acc;
    }
    __syncthreads();

    if (tid < H_) {
        const int h = tid;
        const float qf = q[0][h], q0 = q[1][h], q1 = q[2][h],
                    q62 = q[3][h], q63 = q[4][h];
        const float bw = b_word[h];
        m[0][h] = qf               * (1.f / 64.f) + bw;  // K=1, k=0
        m[1][h] = (qf - q63)       * (1.f / 63.f) + bw;  // K=2, k=0
        m[2][h] = (qf - q0)        * (1.f / 63.f) + bw;  // K=2, k=1
        m[3][h] = (qf - q62 - q63) * (1.f / 62.f) + bw;  // K=3, k=0
        m[4][h] = (qf - q0  - q63) * (1.f / 62.f) + bw;  // K=3, k=1
        m[5][h] = (qf - q0  - q1)  * (1.f / 62.f) + bw;  // K=3, k=2
    }
    __syncthreads();

    if (tid < H_) {
        const int o = tid;
        float a1 = cb1[o], a2 = cb2[o], a3 = cb3[o];
        for (int i = 0; i < H_; ++i) {
            a1 += cw1[o * H_ + i] * m[0][i];
            const float* c2 = cw2 + (o * H_ + i) * 2;
            a2 += c2[0] * m[1][i] + c2[1] * m[2][i];
            const float* c3 = cw3 + (o * H_ + i) * 3;
            a3 += c3[0] * m[3][i] + c3[1] * m[4][i] + c3[2] * m[5][i];
        }
        reps_sh[o] = (tanhf(a1) + tanhf(a2) + tanhf(a3)) * (1.f / 3.f);
    }
    __syncthreads();

    if (tid < 3 * H_) {
        const int g = tid / H_, o = tid % H_;
        const float* Wg = (g == 0) ? Wi : (g == 1) ? Wf : Wr;
        const float* bg = (g == 0) ? bi : (g == 1) ? bf : br;
        float acc = bg[o];
        for (int j = 0; j < H_; ++j) acc += Wg[o * H_ + j] * reps_sh[j];
        Xout[(g * S_ + s) * H_ + o] = acc;
    }
}

// ---------------------------------------------------------------------------
// Kernel 2: the sequential GRNN scan + softmax head. One block, 4 waves:
// wave g in {0,1,2} computes gate g (U rows held in registers, h broadcast
// from LDS), wave 3 applies the state update. 2 barriers per step.
// ---------------------------------------------------------------------------
__global__ __launch_bounds__(256) void k_scan(
    const float* __restrict__ X,   // [3][S_][H_]
    const float* __restrict__ Ui, const float* __restrict__ Uf,
    const float* __restrict__ Ur,
    const float* __restrict__ Wout, const float* __restrict__ bout,
    float* __restrict__ out)
{
    const int tid = threadIdx.x;
    const int wv  = tid >> 6;      // wave id: 0,1,2 = gates i,f,g ; 3 = update
    const int o   = tid & 63;

    __shared__ float h_sh[H_];
    __shared__ float gate[3][H_];
    __shared__ float lg[OUT_];

    float u[H_];
    const bool gate_thread = (wv < 3) && (o < H_);
    const float* Umat = (wv == 0) ? Ui : (wv == 1) ? Uf : Ur;
    if (gate_thread) {
        #pragma unroll
        for (int j = 0; j < H_; ++j) u[j] = Umat[o * H_ + j];
    }
    if (tid < H_) h_sh[tid] = 0.f;
    __syncthreads();

    float xcur = gate_thread ? X[(wv * S_ + 0) * H_ + o] : 0.f;

    for (int t = 0; t < S_; ++t) {
        float xnext = (gate_thread && (t + 1 < S_))
                        ? X[(wv * S_ + t + 1) * H_ + o] : 0.f;
        if (gate_thread) {
            float acc = xcur;
            #pragma unroll
            for (int j = 0; j < H_; ++j) acc += u[j] * h_sh[j];
            float val;
            if (wv < 2) val = 1.f / (1.f + expf(-acc));  // sigmoid gates i,f
            else        val = tanhf(acc);                 // candidate g
            gate[wv][o] = val;
        }
        __syncthreads();
        if (wv == 3 && o < H_) {
            h_sh[o] = tanhf(gate[0][o] * gate[2][o] + gate[1][o] * h_sh[o]);
        }
        __syncthreads();
        xcur = xnext;
    }

    if (tid < OUT_) {
        float acc = bout[tid];
        for (int i = 0; i < H_; ++i) acc += Wout[tid * H_ + i] * h_sh[i];
        lg[tid] = acc;
    }
    __syncthreads();
    if (tid == 0) {
        float mx = lg[0];
        for (int i = 1; i < OUT_; ++i) mx = fmaxf(mx, lg[i]);
        float e[OUT_], sum = 0.f;
        for (int i = 0; i < OUT_; ++i) { e[i] = expf(lg[i] - mx); sum += e[i]; }
        for (int i = 0; i < OUT_; ++i) out[i] = e[i] / sum;
    }
}

extern "C" void kernel_launch(void* const* d_in, const int* in_sizes, int n_in,
                              void* d_out, int out_size, void* d_ws, size_t ws_size,
                              hipStream_t stream) {
    (void)in_sizes; (void)n_in; (void)out_size; (void)ws_size;

    const int*   doc    = (const int*)  d_in[0];
    const float* emb    = (const float*)d_in[1];
    const float* w_word = (const float*)d_in[2];
    const float* b_word = (const float*)d_in[3];
    const float* cw1    = (const float*)d_in[4];
    const float* cb1    = (const float*)d_in[5];
    const float* cw2    = (const float*)d_in[6];
    const float* cb2    = (const float*)d_in[7];
    const float* cw3    = (const float*)d_in[8];
    const float* cb3    = (const float*)d_in[9];
    const float* Wi     = (const float*)d_in[10];
    const float* Ui     = (const float*)d_in[11];
    const float* bi     = (const float*)d_in[12];
    const float* Wf     = (const float*)d_in[13];
    const float* Uf     = (const float*)d_in[14];
    const float* bf     = (const float*)d_in[15];
    const float* Wr     = (const float*)d_in[16];
    const float* Ur     = (const float*)d_in[17];
    const float* br     = (const float*)d_in[18];
    const float* Wout   = (const float*)d_in[19];
    const float* bout   = (const float*)d_in[20];

    float* X = (float*)d_ws;                 // [3][S_][H_] = 76.8 KB
    float* out = (float*)d_out;

    k_sent<<<S_, 256, 0, stream>>>(doc, emb, w_word, b_word,
                                   cw1, cb1, cw2, cb2, cw3, cb3,
                                   Wi, bi, Wf, bf, Wr, br, X);
    k_scan<<<1, 256, 0, stream>>>(X, Ui, Uf, Ur, Wout, bout, out);
}